// Round 1
// 1185.018 us; speedup vs baseline: 1.1375x; 1.1375x over previous
//
#include <hip/hip_runtime.h>
#include <hip/hip_bf16.h>
#include <stdint.h>

typedef __attribute__((ext_vector_type(8))) __bf16 bf16x8;
typedef __attribute__((ext_vector_type(4))) float f32x4;

#define B_TOT   4096
#define NN      20
#define DM      512
#define NC1     1536
#define M_TOT   (B_TOT*NN)   // 81920
#define NPAD    22           // padded node dim: zero row at 0 and 21

__device__ __forceinline__ void async_copy16(const __bf16* g, __bf16* l) {
    __builtin_amdgcn_global_load_lds(
        (__attribute__((address_space(1))) void*)g,
        (__attribute__((address_space(3))) void*)l, 16, 0, 0);
}

// load 8 consecutive elements as float, from either fp32 or bf16 storage
template<typename T>
__device__ __forceinline__ void load8(const T* p, float* r) {
    if constexpr (sizeof(T) == 4) {
        f32x4 a = *(const f32x4*)p;
        f32x4 b = *(const f32x4*)(p + 4);
#pragma unroll
        for (int i = 0; i < 4; ++i) { r[i] = a[i]; r[i + 4] = b[i]; }
    } else {
        bf16x8 a = *(const bf16x8*)p;
#pragma unroll
        for (int i = 0; i < 8; ++i) r[i] = (float)a[i];
    }
}

// ---------------------------------------------------------------------------
// dtype detector: fp32 data has uniform low-16 bits; bf16 pairs have an
// exponent-structured low half. 256 samples, wave-reduced.
// mode: 0 = fp32 storage, 1 = bf16 storage.
// ---------------------------------------------------------------------------
__global__ void detect_kernel(const uint32_t* __restrict__ xw, int* __restrict__ mode) {
    int lane = threadIdx.x & 63;
    int susp = 0;
#pragma unroll
    for (int i = 0; i < 4; ++i) {
        uint32_t w = xw[lane * 4 + i];
        uint32_t e = (w >> 7) & 0xFF;           // exponent of low-half bf16
        if ((e >= 118 && e <= 130) || (w & 0xFFFFu) == 0) susp++;
    }
#pragma unroll
    for (int o = 32; o > 0; o >>= 1) susp += __shfl_xor(susp, o, 64);
    if (lane == 0) *mode = (susp > 128) ? 1 : 0;
}

// ---------------------------------------------------------------------------
// Weight re-layout: Wt[col=p*512+o][k=kap*512+i] = Wp[o,i,kap]  (bf16, B^T)
// plus Wob = bf16(Wo).
// ---------------------------------------------------------------------------
template<typename T>
__device__ __forceinline__ void wt_body(
    const T* __restrict__ Wq, const T* __restrict__ Wk, const T* __restrict__ Wv,
    const T* __restrict__ Wo, __bf16* __restrict__ Wt, __bf16* __restrict__ Wob, int f)
{
    if (f < 1536 * 1536) {
        int col = f / 1536, k = f - col * 1536;
        int p = col >> 9, o = col & 511;
        int kap = k >> 9, i = k & 511;
        const T* W = (p == 0) ? Wq : ((p == 1) ? Wk : Wv);
        Wt[f] = (__bf16)(float)W[(o * 512 + i) * 3 + kap];
    } else {
        int g = f - 1536 * 1536;      // < 262144
        Wob[g] = (__bf16)(float)Wo[g];
    }
}

__global__ __launch_bounds__(256) void wt_kernel(
    const void* Wq, const void* Wk, const void* Wv, const void* Wo,
    __bf16* Wt, __bf16* Wob, const int* mode)
{
    int f = blockIdx.x * 256 + threadIdx.x;   // grid = 10240 blocks = 2,621,440 threads exactly
    if (*mode)
        wt_body<__bf16>((const __bf16*)Wq, (const __bf16*)Wk, (const __bf16*)Wv,
                        (const __bf16*)Wo, Wt, Wob, f);
    else
        wt_body<float>((const float*)Wq, (const float*)Wk, (const float*)Wv,
                       (const float*)Wo, Wt, Wob, f);
}

// ---------------------------------------------------------------------------
// xpad: bf16 copy of x with one zero row before and after each batch item.
// xpad[b][np][i] = (np==0 || np==21) ? 0 : bf16(x[b][np-1][i])
// This makes the conv-GEMM A matrix a contiguous strided view:
//   A[m=(b,n)][k] = xpad[(b*22+n)*512 + k],  k in [0,1536)
// so g1 can stage A with pure global_load_lds (no cvt / ds_write / branches).
// ---------------------------------------------------------------------------
template<typename T>
__device__ __forceinline__ void xpad_body(
    const T* __restrict__ x, __bf16* __restrict__ xp, int idx)
{
    int col = (idx & 63) * 8;      // 0..504
    int row = idx >> 6;            // b*22 + np, np in 0..21
    int b = row / 22;
    int np = row - b * 22;
    bf16x8 ov;
    if (np == 0 || np == 21) {
#pragma unroll
        for (int t = 0; t < 8; ++t) ov[t] = (__bf16)0.f;
    } else {
        float tmp[8];
        load8<T>(x + ((size_t)(b * 20 + np - 1) * 512 + col), tmp);
#pragma unroll
        for (int t = 0; t < 8; ++t) ov[t] = (__bf16)tmp[t];
    }
    *(bf16x8*)(xp + (size_t)row * 512 + col) = ov;
}

__global__ __launch_bounds__(256) void xpad_kernel(
    const void* x, __bf16* xp, const int* mode)
{
    int idx = blockIdx.x * 256 + threadIdx.x;  // grid = 22528 blocks exactly
    if (*mode) xpad_body<__bf16>((const __bf16*)x, xp, idx);
    else       xpad_body<float>((const float*)x, xp, idx);
}

// ---------------------------------------------------------------------------
// qkv conv-GEMM: C[m, c] = sum_k A[m,k] * Wt[c,k]
// A = strided view of xpad (see above). Both operands staged via
// global_load_lds(16B) — structurally identical to g3/m97.
// ---------------------------------------------------------------------------
__global__ __launch_bounds__(256) void g1_kernel(
    const __bf16* __restrict__ xpad, const __bf16* __restrict__ Wt,
    __bf16* __restrict__ Cout, int mbase)
{
    __shared__ __align__(16) __bf16 As[128 * 64];
    __shared__ __align__(16) __bf16 Bs[128 * 64];
    const int tid  = threadIdx.x;
    const int wave = tid >> 6, lane = tid & 63;
    const int n0 = blockIdx.x * 128;
    const int m0 = blockIdx.y * 128;
    const int srow = lane >> 3;          // 0..7
    const int scol = (lane & 7) * 8;
    const int lr = lane & 15, lq = lane >> 4;
    const int wm = (wave >> 1) * 64, wn = (wave & 1) * 64;
    f32x4 acc[4][4] = {};

    // hoisted per-lane source rows (div by 20 once, outside k-loop)
    const __bf16* asrc[4];
    const __bf16* bsrc[4];
#pragma unroll
    for (int j = 0; j < 4; ++j) {
        int r  = wave * 32 + j * 8 + srow;
        int gm = mbase + m0 + r;
        int b  = gm / 20;
        int n  = gm - b * 20;
        asrc[j] = xpad + (size_t)(b * NPAD + n) * 512 + scol;
        bsrc[j] = Wt   + (size_t)(n0 + r) * 1536 + scol;
    }

    for (int kt = 0; kt < 24; ++kt) {
        const int k0 = kt * 64;
        __syncthreads();
#pragma unroll
        for (int j = 0; j < 4; ++j) {
            int rb_ = wave * 32 + j * 8;
            async_copy16(bsrc[j] + k0, Bs + rb_ * 64 + lane * 8);
            async_copy16(asrc[j] + k0, As + rb_ * 64 + lane * 8);
        }
        __syncthreads();
#pragma unroll
        for (int ko = 0; ko < 64; ko += 32) {
            bf16x8 af[4], bfv[4];
#pragma unroll
            for (int mi = 0; mi < 4; ++mi)
                af[mi] = *(const bf16x8*)&As[(wm + mi * 16 + lr) * 64 + ko + lq * 8];
#pragma unroll
            for (int ni = 0; ni < 4; ++ni)
                bfv[ni] = *(const bf16x8*)&Bs[(wn + ni * 16 + lr) * 64 + ko + lq * 8];
#pragma unroll
            for (int mi = 0; mi < 4; ++mi)
#pragma unroll
                for (int ni = 0; ni < 4; ++ni)
                    acc[mi][ni] = __builtin_amdgcn_mfma_f32_16x16x32_bf16(
                        af[mi], bfv[ni], acc[mi][ni], 0, 0, 0);
        }
    }
    // C/D layout: col = lane&15, row = (lane>>4)*4 + reg
#pragma unroll
    for (int mi = 0; mi < 4; ++mi) {
#pragma unroll
        for (int r = 0; r < 4; ++r) {
            int row = m0 + wm + mi * 16 + lq * 4 + r;
            size_t base = (size_t)row * 1536 + n0 + wn + lr;
#pragma unroll
            for (int ni = 0; ni < 4; ++ni)
                Cout[base + ni * 16] = (__bf16)acc[mi][ni][r];
        }
    }
}

// ---------------------------------------------------------------------------
// fused LN + residual + attention. block = one batch item.
// ---------------------------------------------------------------------------
template<typename T>
__device__ __forceinline__ void attn_body(
    const T* __restrict__ x, const __bf16* __restrict__ cqkv,
    const T* __restrict__ lnq_g, const T* __restrict__ lnq_b,
    const T* __restrict__ lnk_g, const T* __restrict__ lnk_b,
    const T* __restrict__ lnv_g, const T* __restrict__ lnv_b,
    const T* __restrict__ rel, __bf16* __restrict__ aout, int bbase,
    __bf16* sq /*[3*20*512]*/, float* S /*[8*20*20]*/, float* rb /*[312]*/)
{
    const int tid = threadIdx.x;
    const int wave = tid >> 6, lane = tid & 63;
    const int bl = blockIdx.x;
    const size_t xbase = (size_t)(bbase + bl) * NN * DM;
    const size_t cbase = (size_t)bl * NN * NC1;

    for (int t = tid; t < 312; t += 256) rb[t] = (float)rel[t];

    // LN + residual: 60 rows (p,n)
    for (int rr = 0; rr < 15; ++rr) {
        int row = wave * 15 + rr;     // 0..59
        int p = row / 20;
        int n = row - p * 20;
        bf16x8 cv = *(const bf16x8*)(cqkv + cbase + (size_t)n * NC1 + p * 512 + lane * 8);
        float vals[8]; float s = 0.f, ss = 0.f;
#pragma unroll
        for (int t = 0; t < 8; ++t) { float f = (float)cv[t]; vals[t] = f; s += f; ss += f * f; }
#pragma unroll
        for (int o = 32; o > 0; o >>= 1) { s += __shfl_xor(s, o, 64); ss += __shfl_xor(ss, o, 64); }
        float mu = s * (1.f / 512.f);
        float var = ss * (1.f / 512.f) - mu * mu;
        float rs = rsqrtf(var + 1e-5f);
        const T* g  = (p == 0) ? lnq_g : (p == 1) ? lnk_g : lnv_g;
        const T* bb = (p == 0) ? lnq_b : (p == 1) ? lnk_b : lnv_b;
        float gv[8], bv[8], xv[8];
        load8<T>(g  + lane * 8, gv);
        load8<T>(bb + lane * 8, bv);
        load8<T>(x + xbase + (size_t)n * DM + lane * 8, xv);
        bf16x8 ov;
#pragma unroll
        for (int t = 0; t < 8; ++t)
            ov[t] = (__bf16)((vals[t] - mu) * rs * gv[t] + bv[t] + xv[t]);
        *(bf16x8*)(sq + ((size_t)p * 20 + n) * 512 + lane * 8) = ov;
    }
    __syncthreads();

    // scores: thread (h, j) holds k-row, loops i
    if (tid < 160) {
        int h = tid / 20, j = tid - (tid / 20) * 20;
        float kreg[64];
        const __bf16* kr = sq + (size_t)(1 * 20 + j) * 512 + h * 64;
#pragma unroll
        for (int t = 0; t < 64; t += 8) {
            bf16x8 kv = *(const bf16x8*)(kr + t);
#pragma unroll
            for (int u = 0; u < 8; ++u) kreg[t + u] = (float)kv[u];
        }
        for (int i = 0; i < 20; ++i) {
            const __bf16* qr = sq + (size_t)(0 * 20 + i) * 512 + h * 64;
            float s = 0.f;
#pragma unroll
            for (int t = 0; t < 64; t += 8) {
                bf16x8 qv = *(const bf16x8*)(qr + t);
#pragma unroll
                for (int u = 0; u < 8; ++u) s += (float)qv[u] * kreg[t + u];
            }
            S[(h * 20 + i) * 20 + j] = s * 0.125f + rb[(i - j + 19) * 8 + h];
        }
    }
    __syncthreads();

    // softmax: thread (h, i)
    if (tid < 160) {
        int h = tid / 20, i = tid - (tid / 20) * 20;
        float* row = &S[(h * 20 + i) * 20];
        float mx = row[0];
        for (int j = 1; j < 20; ++j) mx = fmaxf(mx, row[j]);
        float e[20]; float sum = 0.f;
        for (int j = 0; j < 20; ++j) { e[j] = expf(row[j] - mx); sum += e[j]; }
        float inv = 1.f / sum;
        for (int j = 0; j < 20; ++j) row[j] = e[j] * inv;
    }
    __syncthreads();

    // PV: thread (h, d-pair)
    {
        int h = tid >> 5;
        int d2 = (tid & 31) * 2;
        float v0[20], v1[20];
#pragma unroll
        for (int j = 0; j < 20; ++j) {
            const __bf16* vr = sq + (size_t)(2 * 20 + j) * 512 + h * 64 + d2;
            v0[j] = (float)vr[0]; v1[j] = (float)vr[1];
        }
        for (int i = 0; i < 20; ++i) {
            float o0 = 0.f, o1 = 0.f;
#pragma unroll
            for (int j = 0; j < 20; ++j) {
                float p = S[(h * 20 + i) * 20 + j];
                o0 += p * v0[j]; o1 += p * v1[j];
            }
            __bf16* orow = aout + (size_t)(bl * NN + i) * DM + h * 64 + d2;
            orow[0] = (__bf16)o0;
            orow[1] = (__bf16)o1;
        }
    }
}

__global__ __launch_bounds__(256) void attn_kernel(
    const void* x, const __bf16* cqkv,
    const void* lnq_g, const void* lnq_b, const void* lnk_g, const void* lnk_b,
    const void* lnv_g, const void* lnv_b, const void* rel,
    __bf16* aout, int bbase, const int* mode)
{
    __shared__ __align__(16) __bf16 sq[3 * 20 * 512];  // 61440 B
    __shared__ float S[8 * 20 * 20];                   // 12800 B
    __shared__ float rb[320];
    if (*mode)
        attn_body<__bf16>((const __bf16*)x, cqkv,
            (const __bf16*)lnq_g, (const __bf16*)lnq_b, (const __bf16*)lnk_g,
            (const __bf16*)lnk_b, (const __bf16*)lnv_g, (const __bf16*)lnv_b,
            (const __bf16*)rel, aout, bbase, sq, S, rb);
    else
        attn_body<float>((const float*)x, cqkv,
            (const float*)lnq_g, (const float*)lnq_b, (const float*)lnk_g,
            (const float*)lnk_b, (const float*)lnv_g, (const float*)lnv_b,
            (const float*)rel, aout, bbase, sq, S, rb);
}

// ---------------------------------------------------------------------------
// output projection: out[m,o] = sum_d A[m,d]*Wo[o,d] + bo[o]
// ---------------------------------------------------------------------------
template<typename T>
__device__ __forceinline__ void g3_body(
    const __bf16* __restrict__ Ain, const __bf16* __restrict__ Wob,
    const T* __restrict__ bo, T* __restrict__ out, int mbase,
    __bf16* As, __bf16* Bs)
{
    const int tid  = threadIdx.x;
    const int wave = tid >> 6, lane = tid & 63;
    const int n0 = blockIdx.x * 128;
    const int m0 = blockIdx.y * 128;
    const int srow = lane >> 3;
    const int scol = (lane & 7) * 8;
    const int lr = lane & 15, lq = lane >> 4;
    const int wm = (wave >> 1) * 64, wn = (wave & 1) * 64;
    f32x4 acc[4][4] = {};

    for (int kt = 0; kt < 8; ++kt) {
        const int k0 = kt * 64;
        __syncthreads();
#pragma unroll
        for (int j = 0; j < 4; ++j) {
            int rb_ = wave * 32 + j * 8;
            async_copy16(Ain + (size_t)(m0 + rb_ + srow) * 512 + (k0 + scol),
                         As + rb_ * 64 + lane * 8);
            async_copy16(Wob + (size_t)(n0 + rb_ + srow) * 512 + (k0 + scol),
                         Bs + rb_ * 64 + lane * 8);
        }
        __syncthreads();
#pragma unroll
        for (int ko = 0; ko < 64; ko += 32) {
            bf16x8 af[4], bfv[4];
#pragma unroll
            for (int mi = 0; mi < 4; ++mi)
                af[mi] = *(const bf16x8*)&As[(wm + mi * 16 + lr) * 64 + ko + lq * 8];
#pragma unroll
            for (int ni = 0; ni < 4; ++ni)
                bfv[ni] = *(const bf16x8*)&Bs[(wn + ni * 16 + lr) * 64 + ko + lq * 8];
#pragma unroll
            for (int mi = 0; mi < 4; ++mi)
#pragma unroll
                for (int ni = 0; ni < 4; ++ni)
                    acc[mi][ni] = __builtin_amdgcn_mfma_f32_16x16x32_bf16(
                        af[mi], bfv[ni], acc[mi][ni], 0, 0, 0);
        }
    }
#pragma unroll
    for (int mi = 0; mi < 4; ++mi) {
#pragma unroll
        for (int r = 0; r < 4; ++r) {
            int row = m0 + wm + mi * 16 + lq * 4 + r;
            size_t gbase = (size_t)(mbase + row) * 512 + n0 + wn + lr;
#pragma unroll
            for (int ni = 0; ni < 4; ++ni) {
                float bias = (float)bo[n0 + wn + lr + ni * 16];
                out[gbase + ni * 16] = (T)(acc[mi][ni][r] + bias);
            }
        }
    }
}

__global__ __launch_bounds__(256) void g3_kernel(
    const __bf16* Ain, const __bf16* Wob, const void* bo, void* out,
    int mbase, const int* mode)
{
    __shared__ __align__(16) __bf16 As[128 * 64];
    __shared__ __align__(16) __bf16 Bs[128 * 64];
    if (*mode) g3_body<__bf16>(Ain, Wob, (const __bf16*)bo, (__bf16*)out, mbase, As, Bs);
    else       g3_body<float>(Ain, Wob, (const float*)bo, (float*)out, mbase, As, Bs);
}

// ---------------------------------------------------------------------------
extern "C" void kernel_launch(void* const* d_in, const int* in_sizes, int n_in,
                              void* d_out, int out_size, void* d_ws, size_t ws_size,
                              hipStream_t stream) {
    (void)in_sizes; (void)n_in; (void)out_size;
    char* ws = (char*)d_ws;
    int*    mode = (int*)ws;                               // 256 B reserved
    __bf16* Wt   = (__bf16*)(ws + 256);                    // 4,718,592 B
    __bf16* Wob  = (__bf16*)(ws + 256 + 4718592);          // 524,288 B
    __bf16* xpad = (__bf16*)(ws + 256 + 4718592 + 524288); // 92,274,688 B
    const size_t off_c = 256 + 4718592 + 524288 + (size_t)B_TOT * NPAD * DM * 2;
    // off_c = 97,517,824

    int CH = 1;
    while (CH < 128) {
        size_t rows = (size_t)M_TOT / CH;
        if (off_c + rows * (size_t)NC1 * 2 + rows * (size_t)DM * 2 <= ws_size) break;
        CH *= 2;
    }
    const int rows = M_TOT / CH;       // multiple of 128 for CH in {1..128}
    const int Bc   = B_TOT / CH;
    __bf16* Cbuf = (__bf16*)(ws + off_c);
    __bf16* Abuf = (__bf16*)(ws + off_c + (size_t)rows * NC1 * 2);

    detect_kernel<<<dim3(1), dim3(64), 0, stream>>>((const uint32_t*)d_in[0], mode);
    wt_kernel<<<dim3(10240), dim3(256), 0, stream>>>(
        d_in[1], d_in[2], d_in[3], d_in[11], Wt, Wob, mode);
    xpad_kernel<<<dim3(22528), dim3(256), 0, stream>>>(d_in[0], xpad, mode);

    for (int c = 0; c < CH; ++c) {
        int mbase = c * rows;
        g1_kernel<<<dim3(12, rows / 128), dim3(256), 0, stream>>>(
            xpad, Wt, Cbuf, mbase);
        attn_kernel<<<dim3(Bc), dim3(256), 0, stream>>>(
            d_in[0], Cbuf, d_in[4], d_in[5], d_in[6], d_in[7], d_in[8], d_in[9],
            d_in[10], Abuf, mbase / NN, mode);
        g3_kernel<<<dim3(4, rows / 128), dim3(256), 0, stream>>>(
            Abuf, Wob, d_in[12], d_out, mbase, mode);
    }
}

// Round 2
// 988.633 us; speedup vs baseline: 1.3634x; 1.1986x over previous
//
#include <hip/hip_runtime.h>
#include <hip/hip_bf16.h>
#include <stdint.h>

typedef __attribute__((ext_vector_type(8))) __bf16 bf16x8;
typedef __attribute__((ext_vector_type(4))) float f32x4;

#define B_TOT   4096
#define NN      20
#define DM      512
#define NC1     1536
#define M_TOT   (B_TOT*NN)   // 81920
#define NPAD    22           // padded node dim: zero row at 0 and 21

__device__ __forceinline__ void async_copy16(const __bf16* g, __bf16* l) {
    __builtin_amdgcn_global_load_lds(
        (__attribute__((address_space(1))) void*)g,
        (__attribute__((address_space(3))) void*)l, 16, 0, 0);
}

// load 8 consecutive elements as float, from either fp32 or bf16 storage
template<typename T>
__device__ __forceinline__ void load8(const T* p, float* r) {
    if constexpr (sizeof(T) == 4) {
        f32x4 a = *(const f32x4*)p;
        f32x4 b = *(const f32x4*)(p + 4);
#pragma unroll
        for (int i = 0; i < 4; ++i) { r[i] = a[i]; r[i + 4] = b[i]; }
    } else {
        bf16x8 a = *(const bf16x8*)p;
#pragma unroll
        for (int i = 0; i < 8; ++i) r[i] = (float)a[i];
    }
}

// ---------------------------------------------------------------------------
// dtype detector
// ---------------------------------------------------------------------------
__global__ void detect_kernel(const uint32_t* __restrict__ xw, int* __restrict__ mode) {
    int lane = threadIdx.x & 63;
    int susp = 0;
#pragma unroll
    for (int i = 0; i < 4; ++i) {
        uint32_t w = xw[lane * 4 + i];
        uint32_t e = (w >> 7) & 0xFF;
        if ((e >= 118 && e <= 130) || (w & 0xFFFFu) == 0) susp++;
    }
#pragma unroll
    for (int o = 32; o > 0; o >>= 1) susp += __shfl_xor(susp, o, 64);
    if (lane == 0) *mode = (susp > 128) ? 1 : 0;
}

// ---------------------------------------------------------------------------
// Weight re-layout: Wt[col=p*512+o][k=kap*512+i] = Wp[o,i,kap]  (bf16, B^T)
// ---------------------------------------------------------------------------
template<typename T>
__device__ __forceinline__ void wt_body(
    const T* __restrict__ Wq, const T* __restrict__ Wk, const T* __restrict__ Wv,
    const T* __restrict__ Wo, __bf16* __restrict__ Wt, __bf16* __restrict__ Wob, int f)
{
    if (f < 1536 * 1536) {
        int col = f / 1536, k = f - col * 1536;
        int p = col >> 9, o = col & 511;
        int kap = k >> 9, i = k & 511;
        const T* W = (p == 0) ? Wq : ((p == 1) ? Wk : Wv);
        Wt[f] = (__bf16)(float)W[(o * 512 + i) * 3 + kap];
    } else {
        int g = f - 1536 * 1536;
        Wob[g] = (__bf16)(float)Wo[g];
    }
}

__global__ __launch_bounds__(256) void wt_kernel(
    const void* Wq, const void* Wk, const void* Wv, const void* Wo,
    __bf16* Wt, __bf16* Wob, const int* mode)
{
    int f = blockIdx.x * 256 + threadIdx.x;
    if (*mode)
        wt_body<__bf16>((const __bf16*)Wq, (const __bf16*)Wk, (const __bf16*)Wv,
                        (const __bf16*)Wo, Wt, Wob, f);
    else
        wt_body<float>((const float*)Wq, (const float*)Wk, (const float*)Wv,
                       (const float*)Wo, Wt, Wob, f);
}

// ---------------------------------------------------------------------------
// xpad: bf16 copy of x with one zero row before and after each batch item.
// A[m=(b,n)][k] = xpad[(b*22+n)*512 + k], k in [0,1536)
// ---------------------------------------------------------------------------
template<typename T>
__device__ __forceinline__ void xpad_body(
    const T* __restrict__ x, __bf16* __restrict__ xp, int idx)
{
    int col = (idx & 63) * 8;
    int row = idx >> 6;
    int b = row / 22;
    int np = row - b * 22;
    bf16x8 ov;
    if (np == 0 || np == 21) {
#pragma unroll
        for (int t = 0; t < 8; ++t) ov[t] = (__bf16)0.f;
    } else {
        float tmp[8];
        load8<T>(x + ((size_t)(b * 20 + np - 1) * 512 + col), tmp);
#pragma unroll
        for (int t = 0; t < 8; ++t) ov[t] = (__bf16)tmp[t];
    }
    *(bf16x8*)(xp + (size_t)row * 512 + col) = ov;
}

__global__ __launch_bounds__(256) void xpad_kernel(
    const void* x, __bf16* xp, const int* mode)
{
    int idx = blockIdx.x * 256 + threadIdx.x;
    if (*mode) xpad_body<__bf16>((const __bf16*)x, xp, idx);
    else       xpad_body<float>((const float*)x, xp, idx);
}

// ---------------------------------------------------------------------------
// g1: 256x256-tile 8-phase counted-vmcnt conv-GEMM (T2+T3+T4+T5).
// C[m, c] = sum_k A[m,k] * Wt[c,k];  A = strided view of xpad.
// 512 threads = 8 waves (2M x 4N); per-wave output 128x64.
// LDS 128 KiB: [A|B] x [2 dbuf] x [2 k-halves], each slab 256 rows x 32 cols
// bf16 stored as 16 row-major 16x32 subtiles (1024 B) with st_16x32 XOR
// swizzle (cols ^16 for rows 8..15), inverse applied on the global source
// (global_load_lds dest is linear), forward applied on ds_read -> fragment
// reads are bank-conflict-free.
// Per K-tile (BK=64): 4 phases (kh,qm), 16 MFMA each; one slab staged per
// phase; s_waitcnt vmcnt(4) only at phases 2 and 4 (never drains in loop).
// ---------------------------------------------------------------------------
#define SBAR()  __builtin_amdgcn_s_barrier()
#define SCHED0() __builtin_amdgcn_sched_barrier(0)
#define LGKM0() do { asm volatile("s_waitcnt lgkmcnt(0)" ::: "memory"); SCHED0(); } while (0)
#define VM4()   do { SCHED0(); asm volatile("s_waitcnt vmcnt(4)" ::: "memory"); } while (0)
#define VM0()   do { SCHED0(); asm volatile("s_waitcnt vmcnt(0)" ::: "memory"); } while (0)

__device__ __forceinline__ void g1_loadA(const __bf16* slab, int off, bf16x8 (&aq)[4]) {
#pragma unroll
    for (int i = 0; i < 4; ++i) aq[i] = *(const bf16x8*)(slab + off + i * 512);
}
__device__ __forceinline__ void g1_loadB(const __bf16* slab, int off, bf16x8 (&bq)[4]) {
#pragma unroll
    for (int i = 0; i < 4; ++i) bq[i] = *(const bf16x8*)(slab + off + i * 512);
}
template<int QM>
__device__ __forceinline__ void g1_mma(bf16x8 (&aq)[4], bf16x8 (&bq)[4], f32x4 (&acc)[8][4]) {
    __builtin_amdgcn_s_setprio(1);
#pragma unroll
    for (int i = 0; i < 4; ++i)
#pragma unroll
        for (int nf = 0; nf < 4; ++nf)
            acc[QM * 4 + i][nf] = __builtin_amdgcn_mfma_f32_16x16x32_bf16(
                aq[i], bq[nf], acc[QM * 4 + i][nf], 0, 0, 0);
    __builtin_amdgcn_s_setprio(0);
}

__global__ __launch_bounds__(512, 2) void g1_kernel(
    const __bf16* __restrict__ xpad, const __bf16* __restrict__ Wt,
    __bf16* __restrict__ Cout, int mbase)
{
    extern __shared__ __align__(16) __bf16 sh[];
    __bf16* shA = sh;            // 4 slabs x 8192 bf16 (16 KB each) = 64 KB
    __bf16* shB = sh + 32768;    // 64 KB

    const int tid = threadIdx.x;
    const int w = tid >> 6, l = tid & 63;
    const int lr = l & 15, lq = l >> 4;
    const int wm = w >> 2, wn = w & 3;          // wave grid 2M x 4N

    int nwg = gridDim.x;
    int bid = blockIdx.x;
    if ((nwg & 7) == 0) bid = (bid & 7) * (nwg >> 3) + (bid >> 3);   // XCD swizzle
    const int nb = bid % 6;
    const int mb = bid / 6;
    const int n0 = nb * 256;
    const int mloc = mb * 256;

    // ---- staging source pointers (pre-swizzled logical col) ----
    const int rin = l >> 2;                     // subtile row this thread stages
    const int pc  = (l & 3) * 8;                // physical col (8-chunk)
    const int lc  = (rin >= 8) ? (pc ^ 16) : pc;    // logical col (involution)
    const int R0 = w * 16 + rin;                // tile rows staged: R0, 128+R0
    const int R1 = 128 + R0;
    const int g0 = mbase + mloc + R0, g1r = mbase + mloc + R1;
    const __bf16* aP0 = xpad + (size_t)((g0 / 20) * 22 + g0 % 20) * 512 + lc;
    const __bf16* aP1 = xpad + (size_t)((g1r / 20) * 22 + g1r % 20) * 512 + lc;
    const __bf16* bP0 = Wt + (size_t)(n0 + R0) * 1536 + lc;
    const __bf16* bP1 = Wt + (size_t)(n0 + R1) * 1536 + lc;
    const int sdst = w * 512 + l * 8;           // bf16 index within slab (linear)

    // ---- fragment read offsets (swizzled) ----
    const int swzcol = (lr >= 8) ? ((lq * 8) ^ 16) : (lq * 8);
    const int ardoff = lr * 32 + swzcol;        // bf16 index within subtile
    const int rdA = wm * 8 * 512 + ardoff;      // + QM*2048 + i*512
    const int rdB = wn * 4 * 512 + ardoff;      // + i*512

    f32x4 acc[8][4] = {};
    bf16x8 aq[4], bq[4];

    // ---- prologue: stage tile 0 (kh0 then kh1) into buf 0 ----
    { __bf16* d = shA + 0 * 8192 + sdst; async_copy16(aP0 + 0, d);  async_copy16(aP1 + 0, d + 4096); }
    { __bf16* d = shB + 0 * 8192 + sdst; async_copy16(bP0 + 0, d);  async_copy16(bP1 + 0, d + 4096); }
    { __bf16* d = shA + 1 * 8192 + sdst; async_copy16(aP0 + 32, d); async_copy16(aP1 + 32, d + 4096); }
    { __bf16* d = shB + 1 * 8192 + sdst; async_copy16(bP0 + 32, d); async_copy16(bP1 + 32, d + 4096); }
    VM4();          // kh0 A+B landed; kh1 still in flight
    SBAR();

    for (int t = 0; t < 24; ++t) {
        const int cur = t & 1;
        const __bf16* A0 = shA + (cur * 2 + 0) * 8192;
        const __bf16* A1 = shA + (cur * 2 + 1) * 8192;
        const __bf16* B0 = shB + (cur * 2 + 0) * 8192;
        const __bf16* B1 = shB + (cur * 2 + 1) * 8192;
        __bf16* dA0 = shA + ((cur ^ 1) * 2 + 0) * 8192 + sdst;
        __bf16* dA1 = shA + ((cur ^ 1) * 2 + 1) * 8192 + sdst;
        __bf16* dB0 = shB + ((cur ^ 1) * 2 + 0) * 8192 + sdst;
        __bf16* dB1 = shB + ((cur ^ 1) * 2 + 1) * 8192 + sdst;
        const int kn = (t + 1) * 64;
        const bool st = (t < 23);

        // ---- phase 1: (kh0, qm0) ; stage A(t+1,kh0) ----
        g1_loadA(A0, rdA, aq);
        g1_loadB(B0, rdB, bq);
        if (st) { async_copy16(aP0 + kn, dA0); async_copy16(aP1 + kn, dA0 + 4096); }
        SBAR(); LGKM0();
        g1_mma<0>(aq, bq, acc);
        SBAR();

        // ---- phase 2: (kh0, qm1) ; stage B(t+1,kh0) ; wait ----
        g1_loadA(A0, rdA + 2048, aq);
        if (st) { async_copy16(bP0 + kn, dB0); async_copy16(bP1 + kn, dB0 + 4096); }
        if (st) VM4(); else VM0();     // ensures (t,kh1) A+B landed for phase 3
        SBAR(); LGKM0();
        g1_mma<1>(aq, bq, acc);
        SBAR();

        // ---- phase 3: (kh1, qm0) ; stage A(t+1,kh1) ----
        g1_loadA(A1, rdA, aq);
        g1_loadB(B1, rdB, bq);
        if (st) { async_copy16(aP0 + kn + 32, dA1); async_copy16(aP1 + kn + 32, dA1 + 4096); }
        SBAR(); LGKM0();
        g1_mma<0>(aq, bq, acc);
        SBAR();

        // ---- phase 4: (kh1, qm1) ; stage B(t+1,kh1) ; wait ----
        g1_loadA(A1, rdA + 2048, aq);
        if (st) { async_copy16(bP0 + kn + 32, dB1); async_copy16(bP1 + kn + 32, dB1 + 4096); }
        if (st) VM4();                 // ensures (t+1,kh0) A+B landed for next p1
        SBAR(); LGKM0();
        g1_mma<1>(aq, bq, acc);
        SBAR();
    }

    // C/D layout: col = lane&15, row = (lane>>4)*4 + reg
#pragma unroll
    for (int mf = 0; mf < 8; ++mf) {
#pragma unroll
        for (int r = 0; r < 4; ++r) {
            int row = mloc + wm * 128 + mf * 16 + lq * 4 + r;
            size_t base = (size_t)row * 1536 + n0 + wn * 64 + lr;
#pragma unroll
            for (int nf = 0; nf < 4; ++nf)
                Cout[base + nf * 16] = (__bf16)acc[mf][nf][r];
        }
    }
}

// ---------------------------------------------------------------------------
// fused LN + residual + attention. block = one batch item.
// ---------------------------------------------------------------------------
template<typename T>
__device__ __forceinline__ void attn_body(
    const T* __restrict__ x, const __bf16* __restrict__ cqkv,
    const T* __restrict__ lnq_g, const T* __restrict__ lnq_b,
    const T* __restrict__ lnk_g, const T* __restrict__ lnk_b,
    const T* __restrict__ lnv_g, const T* __restrict__ lnv_b,
    const T* __restrict__ rel, __bf16* __restrict__ aout, int bbase,
    __bf16* sq /*[3*20*512]*/, float* S /*[8*20*20]*/, float* rb /*[312]*/)
{
    const int tid = threadIdx.x;
    const int wave = tid >> 6, lane = tid & 63;
    const int bl = blockIdx.x;
    const size_t xbase = (size_t)(bbase + bl) * NN * DM;
    const size_t cbase = (size_t)bl * NN * NC1;

    for (int t = tid; t < 312; t += 256) rb[t] = (float)rel[t];

    for (int rr = 0; rr < 15; ++rr) {
        int row = wave * 15 + rr;
        int p = row / 20;
        int n = row - p * 20;
        bf16x8 cv = *(const bf16x8*)(cqkv + cbase + (size_t)n * NC1 + p * 512 + lane * 8);
        float vals[8]; float s = 0.f, ss = 0.f;
#pragma unroll
        for (int t = 0; t < 8; ++t) { float f = (float)cv[t]; vals[t] = f; s += f; ss += f * f; }
#pragma unroll
        for (int o = 32; o > 0; o >>= 1) { s += __shfl_xor(s, o, 64); ss += __shfl_xor(ss, o, 64); }
        float mu = s * (1.f / 512.f);
        float var = ss * (1.f / 512.f) - mu * mu;
        float rs = rsqrtf(var + 1e-5f);
        const T* g  = (p == 0) ? lnq_g : (p == 1) ? lnk_g : lnv_g;
        const T* bb = (p == 0) ? lnq_b : (p == 1) ? lnk_b : lnv_b;
        float gv[8], bv[8], xv[8];
        load8<T>(g  + lane * 8, gv);
        load8<T>(bb + lane * 8, bv);
        load8<T>(x + xbase + (size_t)n * DM + lane * 8, xv);
        bf16x8 ov;
#pragma unroll
        for (int t = 0; t < 8; ++t)
            ov[t] = (__bf16)((vals[t] - mu) * rs * gv[t] + bv[t] + xv[t]);
        *(bf16x8*)(sq + ((size_t)p * 20 + n) * 512 + lane * 8) = ov;
    }
    __syncthreads();

    if (tid < 160) {
        int h = tid / 20, j = tid - (tid / 20) * 20;
        float kreg[64];
        const __bf16* kr = sq + (size_t)(1 * 20 + j) * 512 + h * 64;
#pragma unroll
        for (int t = 0; t < 64; t += 8) {
            bf16x8 kv = *(const bf16x8*)(kr + t);
#pragma unroll
            for (int u = 0; u < 8; ++u) kreg[t + u] = (float)kv[u];
        }
        for (int i = 0; i < 20; ++i) {
            const __bf16* qr = sq + (size_t)(0 * 20 + i) * 512 + h * 64;
            float s = 0.f;
#pragma unroll
            for (int t = 0; t < 64; t += 8) {
                bf16x8 qv = *(const bf16x8*)(qr + t);
#pragma unroll
                for (int u = 0; u < 8; ++u) s += (float)qv[u] * kreg[t + u];
            }
            S[(h * 20 + i) * 20 + j] = s * 0.125f + rb[(i - j + 19) * 8 + h];
        }
    }
    __syncthreads();

    if (tid < 160) {
        int h = tid / 20, i = tid - (tid / 20) * 20;
        float* row = &S[(h * 20 + i) * 20];
        float mx = row[0];
        for (int j = 1; j < 20; ++j) mx = fmaxf(mx, row[j]);
        float e[20]; float sum = 0.f;
        for (int j = 0; j < 20; ++j) { e[j] = expf(row[j] - mx); sum += e[j]; }
        float inv = 1.f / sum;
        for (int j = 0; j < 20; ++j) row[j] = e[j] * inv;
    }
    __syncthreads();

    {
        int h = tid >> 5;
        int d2 = (tid & 31) * 2;
        float v0[20], v1[20];
#pragma unroll
        for (int j = 0; j < 20; ++j) {
            const __bf16* vr = sq + (size_t)(2 * 20 + j) * 512 + h * 64 + d2;
            v0[j] = (float)vr[0]; v1[j] = (float)vr[1];
        }
        for (int i = 0; i < 20; ++i) {
            float o0 = 0.f, o1 = 0.f;
#pragma unroll
            for (int j = 0; j < 20; ++j) {
                float p = S[(h * 20 + i) * 20 + j];
                o0 += p * v0[j]; o1 += p * v1[j];
            }
            __bf16* orow = aout + (size_t)(bl * NN + i) * DM + h * 64 + d2;
            orow[0] = (__bf16)o0;
            orow[1] = (__bf16)o1;
        }
    }
}

__global__ __launch_bounds__(256) void attn_kernel(
    const void* x, const __bf16* cqkv,
    const void* lnq_g, const void* lnq_b, const void* lnk_g, const void* lnk_b,
    const void* lnv_g, const void* lnv_b, const void* rel,
    __bf16* aout, int bbase, const int* mode)
{
    __shared__ __align__(16) __bf16 sq[3 * 20 * 512];
    __shared__ float S[8 * 20 * 20];
    __shared__ float rb[320];
    if (*mode)
        attn_body<__bf16>((const __bf16*)x, cqkv,
            (const __bf16*)lnq_g, (const __bf16*)lnq_b, (const __bf16*)lnk_g,
            (const __bf16*)lnk_b, (const __bf16*)lnv_g, (const __bf16*)lnv_b,
            (const __bf16*)rel, aout, bbase, sq, S, rb);
    else
        attn_body<float>((const float*)x, cqkv,
            (const float*)lnq_g, (const float*)lnq_b, (const float*)lnk_g,
            (const float*)lnk_b, (const float*)lnv_g, (const float*)lnv_b,
            (const float*)rel, aout, bbase, sq, S, rb);
}

// ---------------------------------------------------------------------------
// output projection: out[m,o] = sum_d A[m,d]*Wo[o,d] + bo[o]
// ---------------------------------------------------------------------------
template<typename T>
__device__ __forceinline__ void g3_body(
    const __bf16* __restrict__ Ain, const __bf16* __restrict__ Wob,
    const T* __restrict__ bo, T* __restrict__ out, int mbase,
    __bf16* As, __bf16* Bs)
{
    const int tid  = threadIdx.x;
    const int wave = tid >> 6, lane = tid & 63;
    const int n0 = blockIdx.x * 128;
    const int m0 = blockIdx.y * 128;
    const int srow = lane >> 3;
    const int scol = (lane & 7) * 8;
    const int lr = lane & 15, lq = lane >> 4;
    const int wm = (wave >> 1) * 64, wn = (wave & 1) * 64;
    f32x4 acc[4][4] = {};

    for (int kt = 0; kt < 8; ++kt) {
        const int k0 = kt * 64;
        __syncthreads();
#pragma unroll
        for (int j = 0; j < 4; ++j) {
            int rb_ = wave * 32 + j * 8;
            async_copy16(Ain + (size_t)(m0 + rb_ + srow) * 512 + (k0 + scol),
                         As + rb_ * 64 + lane * 8);
            async_copy16(Wob + (size_t)(n0 + rb_ + srow) * 512 + (k0 + scol),
                         Bs + rb_ * 64 + lane * 8);
        }
        __syncthreads();
#pragma unroll
        for (int ko = 0; ko < 64; ko += 32) {
            bf16x8 af[4], bfv[4];
#pragma unroll
            for (int mi = 0; mi < 4; ++mi)
                af[mi] = *(const bf16x8*)&As[(wm + mi * 16 + lr) * 64 + ko + lq * 8];
#pragma unroll
            for (int ni = 0; ni < 4; ++ni)
                bfv[ni] = *(const bf16x8*)&Bs[(wn + ni * 16 + lr) * 64 + ko + lq * 8];
#pragma unroll
            for (int mi = 0; mi < 4; ++mi)
#pragma unroll
                for (int ni = 0; ni < 4; ++ni)
                    acc[mi][ni] = __builtin_amdgcn_mfma_f32_16x16x32_bf16(
                        af[mi], bfv[ni], acc[mi][ni], 0, 0, 0);
        }
    }
#pragma unroll
    for (int mi = 0; mi < 4; ++mi) {
#pragma unroll
        for (int r = 0; r < 4; ++r) {
            int row = m0 + wm + mi * 16 + lq * 4 + r;
            size_t gbase = (size_t)(mbase + row) * 512 + n0 + wn + lr;
#pragma unroll
            for (int ni = 0; ni < 4; ++ni) {
                float bias = (float)bo[n0 + wn + lr + ni * 16];
                out[gbase + ni * 16] = (T)(acc[mi][ni][r] + bias);
            }
        }
    }
}

__global__ __launch_bounds__(256) void g3_kernel(
    const __bf16* Ain, const __bf16* Wob, const void* bo, void* out,
    int mbase, const int* mode)
{
    __shared__ __align__(16) __bf16 As[128 * 64];
    __shared__ __align__(16) __bf16 Bs[128 * 64];
    if (*mode) g3_body<__bf16>(Ain, Wob, (const __bf16*)bo, (__bf16*)out, mbase, As, Bs);
    else       g3_body<float>(Ain, Wob, (const float*)bo, (float*)out, mbase, As, Bs);
}

// ---------------------------------------------------------------------------
extern "C" void kernel_launch(void* const* d_in, const int* in_sizes, int n_in,
                              void* d_out, int out_size, void* d_ws, size_t ws_size,
                              hipStream_t stream) {
    (void)in_sizes; (void)n_in; (void)out_size;
    char* ws = (char*)d_ws;
    int*    mode = (int*)ws;                               // 256 B reserved
    __bf16* Wt   = (__bf16*)(ws + 256);                    // 4,718,592 B
    __bf16* Wob  = (__bf16*)(ws + 256 + 4718592);          // 524,288 B
    __bf16* xpad = (__bf16*)(ws + 256 + 4718592 + 524288); // 92,274,688 B
    const size_t off_c = 256 + 4718592 + 524288 + (size_t)B_TOT * NPAD * DM * 2;

    static bool attr_set = false;
    if (!attr_set) {
        (void)hipFuncSetAttribute((const void*)g1_kernel,
                                  hipFuncAttributeMaxDynamicSharedMemorySize, 131072);
        attr_set = true;
    }

    int CH = 1;
    while (CH < 64) {
        size_t rows = (size_t)M_TOT / CH;
        if (off_c + rows * (size_t)NC1 * 2 + rows * (size_t)DM * 2 <= ws_size) break;
        CH *= 2;
    }
    const int rows = M_TOT / CH;       // multiple of 256 for CH in {1..64}
    const int Bc   = B_TOT / CH;
    __bf16* Cbuf = (__bf16*)(ws + off_c);
    __bf16* Abuf = (__bf16*)(ws + off_c + (size_t)rows * NC1 * 2);

    detect_kernel<<<dim3(1), dim3(64), 0, stream>>>((const uint32_t*)d_in[0], mode);
    wt_kernel<<<dim3(10240), dim3(256), 0, stream>>>(
        d_in[1], d_in[2], d_in[3], d_in[11], Wt, Wob, mode);
    xpad_kernel<<<dim3(22528), dim3(256), 0, stream>>>(d_in[0], xpad, mode);

    for (int c = 0; c < CH; ++c) {
        int mbase = c * rows;
        g1_kernel<<<dim3(6 * (rows / 256)), dim3(512), 131072, stream>>>(
            xpad, Wt, Cbuf, mbase);
        attn_kernel<<<dim3(Bc), dim3(256), 0, stream>>>(
            d_in[0], Cbuf, d_in[4], d_in[5], d_in[6], d_in[7], d_in[8], d_in[9],
            d_in[10], Abuf, mbase / NN, mode);
        g3_kernel<<<dim3(4, rows / 128), dim3(256), 0, stream>>>(
            Abuf, Wob, d_in[12], d_out, mbase, mode);
    }
}